// Round 12
// baseline (450.307 us; speedup 1.0000x reference)
//
#include <hip/hip_runtime.h>

typedef unsigned short u16;
typedef __attribute__((ext_vector_type(8))) short bf16x8;
typedef __attribute__((ext_vector_type(4))) float f32x4;
typedef __attribute__((ext_vector_type(16))) float f32x16;
typedef __attribute__((ext_vector_type(4))) unsigned u32x4;

#define B_ 2
#define N_ 2048
#define C_ 1024
#define H_ 16
#define D_ 64
#define M_ (B_ * N_)  // 4096

// 0.125 * log2(e): fold the 1/sqrt(D) scale and exp->exp2 conversion into Q.
#define QSCALE 0.18033688011114336f

#define EXP2R(x) __builtin_amdgcn_exp2f(x)

__device__ __forceinline__ u16 f2bf(float f) {
    union { float f; unsigned u; } x; x.f = f;
    return (u16)((x.u + 0x8000u) >> 16);
}
__device__ __forceinline__ unsigned pack2bf(float a, float b) {
    union { float f; unsigned u; } x, y; x.f = a; y.f = b;
    return __builtin_amdgcn_perm(y.u + 0x8000u, x.u + 0x8000u, 0x07060302);
}
// single-op pack (RTNE), verified correct in r6
__device__ __forceinline__ unsigned cvtpk2bf(float a, float b) {
    unsigned r;
    asm("v_cvt_pk_bf16_f32 %0, %1, %2" : "=v"(r) : "v"(a), "v"(b));
    return r;
}

__device__ __forceinline__ void async_copy16(const void* gsrc, void* ldst) {
    __builtin_amdgcn_global_load_lds(
        (__attribute__((address_space(1))) void*)gsrc,
        (__attribute__((address_space(3))) void*)ldst,
        16, 0, 0);
}

// Sense-reversing resident-grid barrier (256 blocks, all co-resident by construction).
// bar[0]=count, bar[1]=generation; both zeroed by hipMemsetAsync before launch.
// Releaser resets count BEFORE bumping gen; waiters acquire gen -> see the reset.
__device__ __forceinline__ void gbar(unsigned* bar) {
    __syncthreads();
    __threadfence();  // device-scope: my phase's global writes visible before I'm counted
    if (threadIdx.x == 0) {
        unsigned g = __hip_atomic_load(bar + 1, __ATOMIC_ACQUIRE, __HIP_MEMORY_SCOPE_AGENT);
        unsigned old = __hip_atomic_fetch_add(bar, 1, __ATOMIC_ACQ_REL, __HIP_MEMORY_SCOPE_AGENT);
        if (old == 255) {
            __hip_atomic_store(bar, 0, __ATOMIC_RELAXED, __HIP_MEMORY_SCOPE_AGENT);
            __hip_atomic_fetch_add(bar + 1, 1, __ATOMIC_ACQ_REL, __HIP_MEMORY_SCOPE_AGENT);
        } else {
            while (__hip_atomic_load(bar + 1, __ATOMIC_ACQUIRE, __HIP_MEMORY_SCOPE_AGENT) == g)
                __builtin_amdgcn_s_sleep(2);
        }
    }
    __syncthreads();
}

// ===================== mega-kernel: cast | gemm0(8ph) | attn | gemm1 =====================
// grid 256 x 512, static LDS 128 KB -> exactly 1 block/CU on 256 CUs (residency guaranteed;
// 128 KB static LDS launch proven by r11's gemm_qkv8). Phase bodies are the r11/r9 kernels.
__global__ __launch_bounds__(512, 1) void mega_kernel(
    const float* __restrict__ x, const float* __restrict__ wq,
    const float* __restrict__ wp, const float* __restrict__ bias,
    u16* __restrict__ x_bf, u16* __restrict__ wqkv_bf, u16* __restrict__ wproj_bf,
    u16* __restrict__ q_bf, u16* __restrict__ k_bf, u16* __restrict__ vt_bf,
    u16* __restrict__ ao_bf, float* __restrict__ out, unsigned* bar) {
    __shared__ __align__(16) u16 SL[65536];  // 128 KB, re-used by every phase
    const int tid = threadIdx.x, bid = blockIdx.x;
    const int lane = tid & 63, w = tid >> 6;  // 8 waves

    // ---------------- phase 1: fused f32->bf16 cast, grid-stride over float4s ----------
    for (int i4 = bid * 512 + tid; i4 < 2097152; i4 += 256 * 512) {
        const float* s; u16* d; int j = i4;
        if (j < 1048576)      { s = x;  d = x_bf; }
        else if (j < 1835008) { s = wq; d = wqkv_bf; j -= 1048576; }
        else                  { s = wp; d = wproj_bf; j -= 1835008; }
        const float4 v = *(const float4*)(s + (size_t)j * 4);
        uint2 o;
        o.x = pack2bf(v.x, v.y);
        o.y = pack2bf(v.z, v.w);
        *(uint2*)(d + (size_t)j * 4) = o;
    }
    gbar(bar);

    // ---------------- phase 2: gemm0, 8-phase 256x256 (r11 body), bid<192 --------------
    if (bid < 192) {
        u16* L = SL;  // [region(2)][slot(4)][8192]
        const int wm = w >> 2, wn = w & 3;
        const int q16 = lane >> 4, l15 = lane & 15, l7 = lane & 7;
        const int lr3 = lane >> 3, lc7 = lane & 7;
        const int sbid = (bid & 7) * 24 + (bid >> 3);
        const int bx = sbid % 12, by = sbid / 12;
        const int m0 = by * 256, n0 = bx * 256;
        const int cswz8 = (lc7 ^ lr3) * 8;

        auto stageHT = [&](int t, int isB, int h) {
            if (t > 15) return;
            const u16* src = isB ? wqkv_bf : x_bf;
            int base_row = (isB ? n0 : m0) + h * 128;
#pragma unroll
            for (int i = 0; i < 2; ++i) {
                int c = w * 2 + i;
                async_copy16(src + (size_t)(base_row + c * 8 + lr3) * 1024 + t * 64 + cswz8,
                             (char*)L + ((t & 1) * 4 + isB * 2 + h) * 16384 + c * 1024);
            }
        };

        stageHT(0, 0, 0); stageHT(0, 1, 0); stageHT(0, 1, 1); stageHT(0, 0, 1);
        stageHT(1, 0, 0); stageHT(1, 1, 0); stageHT(1, 1, 1);
        asm volatile("s_waitcnt vmcnt(6)" ::: "memory");
        __builtin_amdgcn_s_barrier();

        f32x4 acc[8][4] = {};
        const int aRow = l15 * 64;
        const int colsw0 = (q16 ^ l7) * 8, colsw1 = ((4 + q16) ^ l7) * 8;
        const u16* LA[2] = { L + (0 * 4 + wm) * 8192, L + (1 * 4 + wm) * 8192 };
        const u16* LB[2] = { L + (0 * 4 + 2 + (wn >> 1)) * 8192, L + (1 * 4 + 2 + (wn >> 1)) * 8192 };
        const int bOff = (wn & 1) * 4096;

        bf16x8 Af[4][2], Bf0[2][2], Bf1[2][2];

        auto readA = [&](int P, int mh) {
#pragma unroll
            for (int i = 0; i < 4; ++i) {
                Af[i][0] = *(const bf16x8*)(LA[P] + (mh * 64 + i * 16) * 64 + aRow + colsw0);
                Af[i][1] = *(const bf16x8*)(LA[P] + (mh * 64 + i * 16) * 64 + aRow + colsw1);
            }
        };
        auto readB = [&](int P, int nh, bf16x8 (*Bf)[2]) {
#pragma unroll
            for (int j = 0; j < 2; ++j) {
                Bf[j][0] = *(const bf16x8*)(LB[P] + bOff + (nh * 32 + j * 16) * 64 + aRow + colsw0);
                Bf[j][1] = *(const bf16x8*)(LB[P] + bOff + (nh * 32 + j * 16) * 64 + aRow + colsw1);
            }
        };
        auto mfma16 = [&](int mh, int nh, bf16x8 (*Bf)[2]) {
            __builtin_amdgcn_s_setprio(1);
#pragma unroll
            for (int i = 0; i < 4; ++i)
#pragma unroll
                for (int j = 0; j < 2; ++j)
#pragma unroll
                    for (int ks = 0; ks < 2; ++ks)
                        acc[mh * 4 + i][nh * 2 + j] = __builtin_amdgcn_mfma_f32_16x16x32_bf16(
                            Af[i][ks], Bf[j][ks], acc[mh * 4 + i][nh * 2 + j], 0, 0, 0);
            __builtin_amdgcn_s_setprio(0);
        };

        for (int it = 0; it < 8; ++it) {
            const int T = 2 * it;
            readA(0, 0); readB(0, 0, Bf0); stageHT(T + 1, 0, 1);
            __builtin_amdgcn_s_barrier();
            mfma16(0, 0, Bf0);
            __builtin_amdgcn_s_barrier();
            readB(0, 1, Bf1);
            __builtin_amdgcn_s_barrier();
            mfma16(0, 1, Bf1);
            __builtin_amdgcn_s_barrier();
            readA(0, 1); stageHT(T + 2, 1, 0);
            __builtin_amdgcn_s_barrier();
            mfma16(1, 1, Bf1);
            __builtin_amdgcn_s_barrier();
            stageHT(T + 2, 1, 1); stageHT(T + 2, 0, 0);
            __builtin_amdgcn_s_barrier();
            mfma16(1, 0, Bf0);
            if (it < 7) { asm volatile("s_waitcnt vmcnt(6)" ::: "memory"); }
            else        { asm volatile("s_waitcnt vmcnt(0)" ::: "memory"); }
            __builtin_amdgcn_s_barrier();
            readA(1, 0); readB(1, 0, Bf0); stageHT(T + 2, 0, 1);
            __builtin_amdgcn_s_barrier();
            mfma16(0, 0, Bf0);
            __builtin_amdgcn_s_barrier();
            readB(1, 1, Bf1);
            __builtin_amdgcn_s_barrier();
            mfma16(0, 1, Bf1);
            __builtin_amdgcn_s_barrier();
            readA(1, 1); stageHT(T + 3, 1, 0);
            __builtin_amdgcn_s_barrier();
            mfma16(1, 1, Bf1);
            __builtin_amdgcn_s_barrier();
            stageHT(T + 3, 1, 1); stageHT(T + 3, 0, 0);
            __builtin_amdgcn_s_barrier();
            mfma16(1, 0, Bf0);
            if (it < 7) { asm volatile("s_waitcnt vmcnt(6)" ::: "memory"); }
            __builtin_amdgcn_s_barrier();
        }

#pragma unroll
        for (int fm = 0; fm < 8; ++fm) {
#pragma unroll
            for (int fn = 0; fn < 4; ++fn) {
                int n_g = n0 + wn * 64 + fn * 16 + l15;
                int which = n_g >> 10;
                int h = (n_g >> 6) & 15;
                int d = n_g & 63;
                int m_base = m0 + wm * 128 + fm * 16 + q16 * 4;
                int b = m_base >> 11;
                int nn0 = m_base & 2047;
                if (which == 2) {
                    uint2 pk;
                    pk.x = pack2bf(acc[fm][fn][0], acc[fm][fn][1]);
                    pk.y = pack2bf(acc[fm][fn][2], acc[fm][fn][3]);
                    *(uint2*)(vt_bf + ((size_t)((b * H_ + h) * D_ + d) << 11) + nn0) = pk;
                } else {
                    size_t base = ((size_t)((b * H_ + h) * N_ + nn0) << 6) + d;
#pragma unroll
                    for (int r = 0; r < 4; ++r) {
                        float v = acc[fm][fn][r];
                        if (which == 0) q_bf[base + (size_t)r * D_] = f2bf(v * QSCALE);
                        else            k_bf[base + (size_t)r * D_] = f2bf(v);
                    }
                }
            }
        }
    }
    gbar(bar);

    // ---------------- phase 3: attention (r11 body), all 256 blocks --------------------
    {
        u16* KsB = SL;            // [2][2][4096] u16 = 32 KB
        u16* VsB = SL + 16384;    // [2][2][4096] u16 = 32 KB
        const int l31 = lane & 31, hi = lane >> 5, l7 = l31 & 7;
        const int bh = (bid & 7) * 4 + (bid >> 6);
        const int q0 = ((bid >> 3) & 7) * 256;
        const size_t head = (size_t)bh * N_ * D_;
        const int lr3 = lane >> 3, lc7 = lane & 7;

        auto stage = [&](int kt, int buf) {
            int key0 = kt * 128;
            int row = w * 8 + lr3;
#pragma unroll
            for (int s = 0; s < 2; ++s) {
                async_copy16(k_bf + head + (size_t)(key0 + s * 64 + row) * D_ + (lc7 ^ lr3) * 8,
                             (char*)(KsB + (buf * 2 + s) * 4096) + w * 1024);
                async_copy16(vt_bf + head + (size_t)row * N_ + key0 + s * 64 + (lc7 ^ lr3) * 8,
                             (char*)(VsB + (buf * 2 + s) * 4096) + w * 1024);
            }
        };

        bf16x8 qf[4];
#pragma unroll
        for (int ds = 0; ds < 4; ++ds)
            qf[ds] = *(const bf16x8*)(q_bf + head + (size_t)(q0 + w * 32 + l31) * D_ + ds * 16 + hi * 8);
        stage(0, 0);
        __builtin_amdgcn_s_waitcnt(0);
        __syncthreads();

        f32x16 o_acc[2] = {};
        float rs = 0.f;

        for (int kt = 0; kt < 16; ++kt) {
            int buf = kt & 1;
            stage((kt + 1) & 15, buf ^ 1);

#pragma unroll
            for (int s = 0; s < 2; ++s) {
                const u16* Kp = KsB + (buf * 2 + s) * 4096;
                const u16* Vp = VsB + (buf * 2 + s) * 4096;
#pragma unroll
                for (int kb2 = 0; kb2 < 2; ++kb2) {
                    f32x16 st = {};
                    __builtin_amdgcn_s_setprio(1);
#pragma unroll
                    for (int ds = 0; ds < 4; ++ds) {
                        bf16x8 kf = *(const bf16x8*)(Kp + (kb2 * 32 + l31) * 64 + ((ds * 2 + hi) ^ l7) * 8);
                        st = __builtin_amdgcn_mfma_f32_32x32x16_bf16(kf, qf[ds], st, 0, 0, 0);
                    }
                    __builtin_amdgcn_s_setprio(0);

                    float p[16];
#pragma unroll
                    for (int i = 0; i < 16; ++i) p[i] = EXP2R(st[i]);
#pragma unroll
                    for (int i = 0; i < 16; ++i) rs += p[i];

                    unsigned a0 = cvtpk2bf(p[0], p[1]),   b0 = cvtpk2bf(p[4], p[5]);
                    unsigned a1 = cvtpk2bf(p[2], p[3]),   b1 = cvtpk2bf(p[6], p[7]);
                    unsigned a2 = cvtpk2bf(p[8], p[9]),   b2 = cvtpk2bf(p[12], p[13]);
                    unsigned a3 = cvtpk2bf(p[10], p[11]), b3 = cvtpk2bf(p[14], p[15]);
                    asm("v_permlane32_swap_b32 %0, %1" : "+v"(a0), "+v"(b0));
                    asm("v_permlane32_swap_b32 %0, %1" : "+v"(a1), "+v"(b1));
                    asm("v_permlane32_swap_b32 %0, %1" : "+v"(a2), "+v"(b2));
                    asm("v_permlane32_swap_b32 %0, %1" : "+v"(a3), "+v"(b3));
                    union { u32x4 u; bf16x8 v; } af0, af1;
                    af0.u = (u32x4){a0, a1, b0, b1};
                    af1.u = (u32x4){a2, a3, b2, b3};

                    __builtin_amdgcn_s_setprio(1);
#pragma unroll
                    for (int db = 0; db < 2; ++db) {
                        bf16x8 vf0 = *(const bf16x8*)(Vp + (db * 32 + l31) * 64 + ((kb2 * 4 + hi) ^ l7) * 8);
                        o_acc[db] = __builtin_amdgcn_mfma_f32_32x32x16_bf16(af0.v, vf0, o_acc[db], 0, 0, 0);
                        bf16x8 vf1 = *(const bf16x8*)(Vp + (db * 32 + l31) * 64 + ((kb2 * 4 + 2 + hi) ^ l7) * 8);
                        o_acc[db] = __builtin_amdgcn_mfma_f32_32x32x16_bf16(af1.v, vf1, o_acc[db], 0, 0, 0);
                    }
                    __builtin_amdgcn_s_setprio(0);
                }
            }

            __builtin_amdgcn_s_waitcnt(0);
            __syncthreads();
        }

        rs += __shfl_xor(rs, 32);
        float rsi = 1.0f / rs;
        const int b = bh >> 4, h = bh & 15;
#pragma unroll
        for (int reg = 0; reg < 16; ++reg) {
            int qrow = (reg & 3) + 8 * (reg >> 2) + 4 * hi;
            float inv = __shfl(rsi, qrow);
            int qg = q0 + w * 32 + qrow;
#pragma unroll
            for (int db = 0; db < 2; ++db) {
                int d = db * 32 + l31;
                ao_bf[((size_t)(b * N_ + qg) << 10) + h * 64 + d] = f2bf(o_acc[db][reg] * inv);
            }
        }
    }
    gbar(bar);

    // ---------------- phase 4: gemm1 (r9 body), 512 tiles = 2 x 4-wave groups/block ----
    {
        const int grp = w >> 2, wv = w & 2 ? (w & 3) : (w & 3);  // wv = w & 3
        const int wv3 = w & 3;
        u16* As = SL + grp * 12288;          // 16 KB per group (in u16: 8192)
        u16* Bs = SL + grp * 12288 + 8192;   // 8 KB per group (in u16: 4096)
        const int v = bid * 2 + grp;
        const int sbid = (v & 7) * 64 + (v >> 3);
        const int bx = sbid & 15, by = sbid >> 4;
        const int m0 = by * 128, n0 = bx * 64;
        const int wm = wv3 >> 1, wn = wv3 & 1;
        const int q16 = lane >> 4, l15 = lane & 15;
        const int r0 = lane >> 3, c0 = (lane & 7) * 8;
        f32x4 acc[4][2] = {};

        for (int k0 = 0; k0 < C_; k0 += 64) {
#pragma unroll
            for (int i = 0; i < 4; ++i) {
                int blk = wv3 * 4 + i;
                int r = blk * 8 + r0;
                async_copy16(ao_bf + (size_t)(m0 + r) * C_ + k0 + c0, (char*)As + blk * 1024);
            }
#pragma unroll
            for (int i = 0; i < 2; ++i) {
                int blk = wv3 * 2 + i;
                int r = blk * 8 + r0;
                async_copy16(wproj_bf + (size_t)(n0 + r) * C_ + k0 + c0, (char*)Bs + blk * 1024);
            }
            __builtin_amdgcn_s_waitcnt(0);
            __syncthreads();
#pragma unroll
            for (int ks = 0; ks < 2; ++ks) {
                bf16x8 af[4], bf[2];
#pragma unroll
                for (int i = 0; i < 4; ++i)
                    af[i] = *(const bf16x8*)(As + (wm * 64 + i * 16 + l15) * 64 + ks * 32 + q16 * 8);
#pragma unroll
                for (int i = 0; i < 2; ++i)
                    bf[i] = *(const bf16x8*)(Bs + (wn * 32 + i * 16 + l15) * 64 + ks * 32 + q16 * 8);
#pragma unroll
                for (int mi = 0; mi < 4; ++mi)
#pragma unroll
                    for (int ni = 0; ni < 2; ++ni)
                        acc[mi][ni] = __builtin_amdgcn_mfma_f32_16x16x32_bf16(af[mi], bf[ni], acc[mi][ni], 0, 0, 0);
            }
            __syncthreads();
        }

#pragma unroll
        for (int mi = 0; mi < 4; ++mi) {
#pragma unroll
            for (int ni = 0; ni < 2; ++ni) {
                int n_g = n0 + wn * 32 + ni * 16 + l15;
#pragma unroll
                for (int r = 0; r < 4; ++r) {
                    int m_g = m0 + wm * 64 + mi * 16 + q16 * 4 + r;
                    out[(size_t)m_g * C_ + n_g] = acc[mi][ni][r] + bias[n_g];
                }
            }
        }
    }
}

// =================== fallback path (proven r11 4-kernel pipeline) ===================
__global__ void cast3_kernel(const float* __restrict__ x, const float* __restrict__ wq,
                             const float* __restrict__ wp, u16* __restrict__ xo,
                             u16* __restrict__ wqo, u16* __restrict__ wpo) {
    int b = blockIdx.x;
    const float* s; u16* d;
    if (b < 4096)      { s = x;  d = xo;  }
    else if (b < 7168) { s = wq; d = wqo; b -= 4096; }
    else               { s = wp; d = wpo; b -= 7168; }
    int i = (b * 256 + threadIdx.x) * 4;
    const float4 v = *(const float4*)(s + i);
    uint2 o;
    o.x = pack2bf(v.x, v.y);
    o.y = pack2bf(v.z, v.w);
    *(uint2*)(d + i) = o;
}

__global__ __launch_bounds__(256, 3) void gemm_qkv(
    const u16* __restrict__ A, const u16* __restrict__ Bm,
    u16* __restrict__ qo, u16* __restrict__ ko, u16* __restrict__ vt) {
    __shared__ u16 As[128 * 64];
    __shared__ u16 Bs[128 * 64];
    const int K = C_, ntiles_n = 24;
    const int tid = threadIdx.x, lane = tid & 63, w = tid >> 6;
    const int cpx = gridDim.x >> 3;
    const int sbid = (blockIdx.x & 7) * cpx + (blockIdx.x >> 3);
    const int bx = sbid % ntiles_n, by = sbid / ntiles_n;
    const int m0 = by * 128, n0 = bx * 128;
    const int wm = w >> 1, wn = w & 1;
    const int q16 = lane >> 4, l15 = lane & 15;
    const int r0 = lane >> 3, c0 = (lane & 7) * 8;
    f32x4 acc[4][4] = {};

    for (int k0 = 0; k0 < K; k0 += 64) {
#pragma unroll
        for (int i = 0; i < 4; ++i) {
            int blk = w * 4 + i;
            int r = blk * 8 + r0;
            async_copy16(A + (size_t)(m0 + r) * K + k0 + c0, (char*)As + blk * 1024);
            async_copy16(Bm + (size_t)(n0 + r) * K + k0 + c0, (char*)Bs + blk * 1024);
        }
        __builtin_amdgcn_s_waitcnt(0);
        __syncthreads();
#pragma unroll
        for (int ks = 0; ks < 2; ++ks) {
            bf16x8 af[4], bf[4];
#pragma unroll
            for (int i = 0; i < 4; ++i) {
                af[i] = *(const bf16x8*)&As[(wm * 64 + i * 16 + l15) * 64 + ks * 32 + q16 * 8];
                bf[i] = *(const bf16x8*)&Bs[(wn * 64 + i * 16 + l15) * 64 + ks * 32 + q16 * 8];
            }
#pragma unroll
            for (int mi = 0; mi < 4; ++mi)
#pragma unroll
                for (int ni = 0; ni < 4; ++ni)
                    acc[mi][ni] = __builtin_amdgcn_mfma_f32_16x16x32_bf16(af[mi], bf[ni], acc[mi][ni], 0, 0, 0);
        }
        __syncthreads();
    }

#pragma unroll
    for (int mi = 0; mi < 4; ++mi) {
#pragma unroll
        for (int ni = 0; ni < 4; ++ni) {
            int n_g = n0 + wn * 64 + ni * 16 + l15;
            int which = n_g >> 10;
            int h = (n_g >> 6) & 15;
            int d = n_g & 63;
            int m_base = m0 + wm * 64 + mi * 16 + q16 * 4;
            int b = m_base >> 11;
            int nn0 = m_base & 2047;
            if (which == 2) {
                uint2 pk;
                pk.x = pack2bf(acc[mi][ni][0], acc[mi][ni][1]);
                pk.y = pack2bf(acc[mi][ni][2], acc[mi][ni][3]);
                *(uint2*)(vt + ((size_t)((b * H_ + h) * D_ + d) << 11) + nn0) = pk;
            } else {
                size_t base = ((size_t)((b * H_ + h) * N_ + nn0) << 6) + d;
#pragma unroll
                for (int r = 0; r < 4; ++r) {
                    float v = acc[mi][ni][r];
                    if (which == 0) qo[base + (size_t)r * D_] = f2bf(v * QSCALE);
                    else            ko[base + (size_t)r * D_] = f2bf(v);
                }
            }
        }
    }
}

__global__ __launch_bounds__(256, 2) void gemm_out_k(
    const u16* __restrict__ A, const u16* __restrict__ Bm,
    const float* __restrict__ bias, float* __restrict__ out) {
    __shared__ u16 As[128 * 64];
    __shared__ u16 Bs[64 * 64];
    const int K = C_, Ncols = C_, ntiles_n = 16;
    const int tid = threadIdx.x, lane = tid & 63, w = tid >> 6;
    const int cpx = gridDim.x >> 3;
    const int sbid = (blockIdx.x & 7) * cpx + (blockIdx.x >> 3);
    const int bx = sbid % ntiles_n, by = sbid / ntiles_n;
    const int m0 = by * 128, n0 = bx * 64;
    const int wm = w >> 1, wn = w & 1;
    const int q16 = lane >> 4, l15 = lane & 15;
    const int r0 = lane >> 3, c0 = (lane & 7) * 8;
    f32x4 acc[4][2] = {};

    for (int k0 = 0; k0 < K; k0 += 64) {
#pragma unroll
        for (int i = 0; i < 4; ++i) {
            int blk = w * 4 + i;
            int r = blk * 8 + r0;
            async_copy16(A + (size_t)(m0 + r) * K + k0 + c0, (char*)As + blk * 1024);
        }
#pragma unroll
        for (int i = 0; i < 2; ++i) {
            int blk = w * 2 + i;
            int r = blk * 8 + r0;
            async_copy16(Bm + (size_t)(n0 + r) * K + k0 + c0, (char*)Bs + blk * 1024);
        }
        __builtin_amdgcn_s_waitcnt(0);
        __syncthreads();
#pragma unroll
        for (int ks = 0; ks < 2; ++ks) {
            bf16x8 af[4], bf[2];
#pragma unroll
            for (int i = 0; i < 4; ++i)
                af[i] = *(const bf16x8*)&As[(wm * 64 + i * 16 + l15) * 64 + ks * 32 + q16 * 8];
#pragma unroll
            for (int i = 0; i < 2; ++i)
                bf[i] = *(const bf16x8*)&Bs[(wn * 32 + i * 16 + l15) * 64 + ks * 32 + q16 * 8];
#pragma unroll
            for (int mi = 0; mi < 4; ++mi)
#pragma unroll
                for (int ni = 0; ni < 2; ++ni)
                    acc[mi][ni] = __builtin_amdgcn_mfma_f32_16x16x32_bf16(af[mi], bf[ni], acc[mi][ni], 0, 0, 0);
        }
        __syncthreads();
    }

#pragma unroll
    for (int mi = 0; mi < 4; ++mi) {
#pragma unroll
        for (int ni = 0; ni < 2; ++ni) {
            int n_g = n0 + wn * 32 + ni * 16 + l15;
#pragma unroll
            for (int r = 0; r < 4; ++r) {
                int m_g = m0 + wm * 64 + mi * 16 + q16 * 4 + r;
                out[(size_t)m_g * Ncols + n_g] = acc[mi][ni][r] + bias[n_g];
            }
        }
    }
}

__global__ __launch_bounds__(512, 1) void attn_kernel(
    const u16* __restrict__ Q, const u16* __restrict__ K,
    const u16* __restrict__ VT, u16* __restrict__ O) {
    __shared__ u16 Ks[2][2][64 * 64];
    __shared__ u16 Vs[2][2][64 * 64];
    const int tid = threadIdx.x, lane = tid & 63, w = tid >> 6;
    const int l31 = lane & 31, hi = lane >> 5, l7 = l31 & 7;
    const int bid = blockIdx.x;
    const int bh = (bid & 7) * 4 + (bid >> 6);
    const int q0 = ((bid >> 3) & 7) * 256;
    const size_t head = (size_t)bh * N_ * D_;
    const int lr3 = lane >> 3, lc7 = lane & 7;

    auto stage = [&](int kt, int buf) {
        int key0 = kt * 128;
        int row = w * 8 + lr3;
#pragma unroll
        for (int s = 0; s < 2; ++s) {
            async_copy16(K + head + (size_t)(key0 + s * 64 + row) * D_ + (lc7 ^ lr3) * 8,
                         (char*)Ks[buf][s] + w * 1024);
            async_copy16(VT + head + (size_t)row * N_ + key0 + s * 64 + (lc7 ^ lr3) * 8,
                         (char*)Vs[buf][s] + w * 1024);
        }
    };

    bf16x8 qf[4];
#pragma unroll
    for (int ds = 0; ds < 4; ++ds)
        qf[ds] = *(const bf16x8*)(Q + head + (size_t)(q0 + w * 32 + l31) * D_ + ds * 16 + hi * 8);
    stage(0, 0);
    __builtin_amdgcn_s_waitcnt(0);
    __syncthreads();

    f32x16 o_acc[2] = {};
    float rs = 0.f;

    for (int kt = 0; kt < 16; ++kt) {
        int buf = kt & 1;
        stage((kt + 1) & 15, buf ^ 1);

#pragma unroll
        for (int s = 0; s < 2; ++s) {
#pragma unroll
            for (int kb2 = 0; kb2 < 2; ++kb2) {
                f32x16 st = {};
                __builtin_amdgcn_s_setprio(1);
#pragma unroll
                for (int ds = 0; ds < 4; ++ds) {
                    bf16x8 kf = *(const bf16x8*)&Ks[buf][s][(kb2 * 32 + l31) * 64 + ((ds * 2 + hi) ^ l7) * 8];
                    st = __builtin_amdgcn_mfma_f32_32x32x16_bf16(kf, qf[ds], st, 0, 0, 0);
                }
                __builtin_amdgcn_s_setprio(0);

                float p[16];
#pragma unroll
                for (int i = 0; i < 16; ++i) p[i] = EXP2R(st[i]);
#pragma unroll
                for (int i = 0; i < 16; ++i) rs += p[i];

                unsigned a0 = cvtpk2bf(p[0], p[1]),   b0 = cvtpk2bf(p[4], p[5]);
                unsigned a1 = cvtpk2bf(p[2], p[3]),   b1 = cvtpk2bf(p[6], p[7]);
                unsigned a2 = cvtpk2bf(p[8], p[9]),   b2 = cvtpk2bf(p[12], p[13]);
                unsigned a3 = cvtpk2bf(p[10], p[11]), b3 = cvtpk2bf(p[14], p[15]);
                asm("v_permlane32_swap_b32 %0, %1" : "+v"(a0), "+v"(b0));
                asm("v_permlane32_swap_b32 %0, %1" : "+v"(a1), "+v"(b1));
                asm("v_permlane32_swap_b32 %0, %1" : "+v"(a2), "+v"(b2));
                asm("v_permlane32_swap_b32 %0, %1" : "+v"(a3), "+v"(b3));
                union { u32x4 u; bf16x8 v; } af0, af1;
                af0.u = (u32x4){a0, a1, b0, b1};
                af1.u = (u32x4){a2, a3, b2, b3};

                __builtin_amdgcn_s_setprio(1);
#pragma unroll
                for (int db = 0; db < 2; ++db) {
                    bf16x8 vf0 = *(const bf16x8*)&Vs[buf][s][(db * 32 + l31) * 64 + ((kb2 * 4 + hi) ^ l7) * 8];
                    o_acc[db] = __builtin_amdgcn_mfma_f32_32x32x16_bf16(af0.v, vf0, o_acc[db], 0, 0, 0);
                    bf16x8 vf1 = *(const bf16x8*)&Vs[buf][s][(db * 32 + l31) * 64 + ((kb2 * 4 + 2 + hi) ^ l7) * 8];
                    o_acc[db] = __builtin_amdgcn_mfma_f32_32x32x16_bf16(af1.v, vf1, o_acc[db], 0, 0, 0);
                }
                __builtin_amdgcn_s_setprio(0);
            }
        }

        __builtin_amdgcn_s_waitcnt(0);
        __syncthreads();
    }

    rs += __shfl_xor(rs, 32);
    float rsi = 1.0f / rs;

    const int b = bh >> 4, h = bh & 15;
#pragma unroll
    for (int reg = 0; reg < 16; ++reg) {
        int qrow = (reg & 3) + 8 * (reg >> 2) + 4 * hi;
        float inv = __shfl(rsi, qrow);
        int qg = q0 + w * 32 + qrow;
#pragma unroll
        for (int db = 0; db < 2; ++db) {
            int d = db * 32 + l31;
            O[((size_t)(b * N_ + qg) << 10) + h * 64 + d] = f2bf(o_acc[db][reg] * inv);
        }
    }
}

extern "C" void kernel_launch(void* const* d_in, const int* in_sizes, int n_in,
                              void* d_out, int out_size, void* d_ws, size_t ws_size,
                              hipStream_t stream) {
    const float* x      = (const float*)d_in[0];
    const float* w_qkv  = (const float*)d_in[1];
    const float* w_proj = (const float*)d_in[2];
    const float* b_proj = (const float*)d_in[3];
    float* out = (float*)d_out;

    char* ws = (char*)d_ws;
    const size_t MB = 1024 * 1024;
    u16* x_bf     = (u16*)(ws + 0 * MB);   // 8 MB
    u16* wqkv_bf  = (u16*)(ws + 8 * MB);   // 6 MB
    u16* wproj_bf = (u16*)(ws + 14 * MB);  // 2 MB
    u16* q_bf     = (u16*)(ws + 16 * MB);  // 8 MB [B,H,N,D]
    u16* k_bf     = (u16*)(ws + 24 * MB);  // 8 MB [B,H,N,D]
    u16* vt_bf    = (u16*)(ws + 32 * MB);  // 8 MB [B,H,D,N]
    u16* ao_bf    = (u16*)(ws + 40 * MB);  // 8 MB [B,N,C]

    if (ws_size >= 48 * MB + 64) {
        unsigned* bar = (unsigned*)(ws + 48 * MB);
        hipMemsetAsync(bar, 0, 64, stream);  // stream-ordered, graph-capture-legal
        mega_kernel<<<256, 512, 0, stream>>>(x, w_qkv, w_proj, b_proj,
                                             x_bf, wqkv_bf, wproj_bf,
                                             q_bf, k_bf, vt_bf, ao_bf, out, bar);
    } else {
        cast3_kernel<<<8192, 256, 0, stream>>>(x, w_qkv, w_proj, x_bf, wqkv_bf, wproj_bf);
        gemm_qkv<<<768, 256, 0, stream>>>(x_bf, wqkv_bf, q_bf, k_bf, vt_bf);
        attn_kernel<<<256, 512, 0, stream>>>(q_bf, k_bf, vt_bf, ao_bf);
        gemm_out_k<<<512, 256, 0, stream>>>(ao_bf, wproj_bf, b_proj, out);
    }
}

// Round 14
// 179.640 us; speedup vs baseline: 2.5067x; 2.5067x over previous
//
#include <hip/hip_runtime.h>

typedef unsigned short u16;
typedef __attribute__((ext_vector_type(8))) short bf16x8;
typedef __attribute__((ext_vector_type(4))) float f32x4;
typedef __attribute__((ext_vector_type(16))) float f32x16;
typedef __attribute__((ext_vector_type(4))) unsigned u32x4;

#define B_ 2
#define N_ 2048
#define C_ 1024
#define H_ 16
#define D_ 64
#define M_ (B_ * N_)  // 4096

// 0.125 * log2(e): fold the 1/sqrt(D) scale and exp->exp2 conversion into Q.
#define QSCALE 0.18033688011114336f

#define EXP2R(x) __builtin_amdgcn_exp2f(x)

__device__ __forceinline__ u16 f2bf(float f) {
    union { float f; unsigned u; } x; x.f = f;
    return (u16)((x.u + 0x8000u) >> 16);
}
__device__ __forceinline__ unsigned pack2bf(float a, float b) {
    union { float f; unsigned u; } x, y; x.f = a; y.f = b;
    return __builtin_amdgcn_perm(y.u + 0x8000u, x.u + 0x8000u, 0x07060302);
}
// single-op pack (RTNE), verified correct in r6
__device__ __forceinline__ unsigned cvtpk2bf(float a, float b) {
    unsigned r;
    asm("v_cvt_pk_bf16_f32 %0, %1, %2" : "=v"(r) : "v"(a), "v"(b));
    return r;
}

__device__ __forceinline__ void async_copy16(const void* gsrc, void* ldst) {
    __builtin_amdgcn_global_load_lds(
        (__attribute__((address_space(1))) void*)gsrc,
        (__attribute__((address_space(3))) void*)ldst,
        16, 0, 0);
}

// ---------------- fused cast fp32 -> bf16 (x, w_qkv, w_proj in one launch) ----------------
__global__ void cast3_kernel(const float* __restrict__ x, const float* __restrict__ wq,
                             const float* __restrict__ wp, u16* __restrict__ xo,
                             u16* __restrict__ wqo, u16* __restrict__ wpo) {
    int b = blockIdx.x;
    const float* s; u16* d;
    if (b < 4096)      { s = x;  d = xo;  }
    else if (b < 7168) { s = wq; d = wqo; b -= 4096; }
    else               { s = wp; d = wpo; b -= 7168; }
    int i = (b * 256 + threadIdx.x) * 4;
    const float4 v = *(const float4*)(s + i);
    uint2 o;
    o.x = pack2bf(v.x, v.y);
    o.y = pack2bf(v.z, v.w);
    *(uint2*)(d + i) = o;
}

// ---------------- gemm0: 8-phase 256x256 schedule (r11, verified WAR-safe) ----------------
// C = A(x_bf [4096,1024]) * B(wqkv_bf [3072,1024])^T, scatter epilogue into q/k/vt.
// grid 192 (16x12), 512 thr (8 waves, 2M x 4N), LDS 128 KB = 2 regions x 4 half-tile slots
// {Ah0,Ah1,Bh0,Bh1} of [128][64] bf16, XOR-swizzled (source (lc7^lr3), read ^l7).
// Ledger: A slots read in ph1+ph3 -> Ah0 stages at ph4/ph8; B slots read ph1+ph2 -> Bh0 at
// ph3/ph7, Bh1 at ph4/ph8. vmcnt(6) at ph4/ph8 completes the next tile before its reads.
__global__ __launch_bounds__(512, 2) void gemm_qkv8(
    const u16* __restrict__ A, const u16* __restrict__ Bm,
    u16* __restrict__ qo, u16* __restrict__ ko, u16* __restrict__ vt) {
    __shared__ u16 L[2][4][8192];  // [region][slot][128*64]
    const int tid = threadIdx.x, lane = tid & 63, w = tid >> 6;  // 8 waves
    const int wm = w >> 2, wn = w & 3;
    const int q16 = lane >> 4, l15 = lane & 15, l7 = lane & 7;
    const int lr3 = lane >> 3, lc7 = lane & 7;
    const int sbid = (blockIdx.x & 7) * 24 + (blockIdx.x >> 3);  // XCD swizzle (192%8==0)
    const int bx = sbid % 12, by = sbid / 12;
    const int m0 = by * 256, n0 = bx * 256;
    const int cswz8 = (lc7 ^ lr3) * 8;

    auto stageHT = [&](int t, int isB, int h) {  // one 16KB half-tile, 2 loads/thread
        if (t > 15) return;
        const u16* src = isB ? Bm : A;
        int base_row = (isB ? n0 : m0) + h * 128;
#pragma unroll
        for (int i = 0; i < 2; ++i) {
            int c = w * 2 + i;  // 1KB chunk 0..15 (8 rows x 128B)
            async_copy16(src + (size_t)(base_row + c * 8 + lr3) * 1024 + t * 64 + cswz8,
                         (char*)L + ((t & 1) * 4 + isB * 2 + h) * 16384 + c * 1024);
        }
    };

    // prologue: tile0 (4 halves) + tile1 (3 halves); drain to 3 HT; barrier.
    stageHT(0, 0, 0); stageHT(0, 1, 0); stageHT(0, 1, 1); stageHT(0, 0, 1);
    stageHT(1, 0, 0); stageHT(1, 1, 0); stageHT(1, 1, 1);
    asm volatile("s_waitcnt vmcnt(6)" ::: "memory");
    __builtin_amdgcn_s_barrier();

    f32x4 acc[8][4] = {};
    const int aRow = l15 * 64;
    const int colsw0 = (q16 ^ l7) * 8, colsw1 = ((4 + q16) ^ l7) * 8;
    const u16* LA[2] = { &L[0][wm][0], &L[1][wm][0] };
    const u16* LB[2] = { &L[0][2 + (wn >> 1)][0], &L[1][2 + (wn >> 1)][0] };
    const int bOff = (wn & 1) * 4096;

    bf16x8 Af[4][2], Bf0[2][2], Bf1[2][2];

    auto readA = [&](int P, int mh) {
#pragma unroll
        for (int i = 0; i < 4; ++i) {
            Af[i][0] = *(const bf16x8*)(LA[P] + (mh * 64 + i * 16) * 64 + aRow + colsw0);
            Af[i][1] = *(const bf16x8*)(LA[P] + (mh * 64 + i * 16) * 64 + aRow + colsw1);
        }
    };
    auto readB = [&](int P, int nh, bf16x8 (*Bf)[2]) {
#pragma unroll
        for (int j = 0; j < 2; ++j) {
            Bf[j][0] = *(const bf16x8*)(LB[P] + bOff + (nh * 32 + j * 16) * 64 + aRow + colsw0);
            Bf[j][1] = *(const bf16x8*)(LB[P] + bOff + (nh * 32 + j * 16) * 64 + aRow + colsw1);
        }
    };
    auto mfma16 = [&](int mh, int nh, bf16x8 (*Bf)[2]) {
        __builtin_amdgcn_s_setprio(1);
#pragma unroll
        for (int i = 0; i < 4; ++i)
#pragma unroll
            for (int j = 0; j < 2; ++j)
#pragma unroll
                for (int ks = 0; ks < 2; ++ks)
                    acc[mh * 4 + i][nh * 2 + j] = __builtin_amdgcn_mfma_f32_16x16x32_bf16(
                        Af[i][ks], Bf[j][ks], acc[mh * 4 + i][nh * 2 + j], 0, 0, 0);
        __builtin_amdgcn_s_setprio(0);
    };

    for (int it = 0; it < 8; ++it) {
        const int T = 2 * it;
        readA(0, 0); readB(0, 0, Bf0); stageHT(T + 1, 0, 1);
        __builtin_amdgcn_s_barrier();
        mfma16(0, 0, Bf0);
        __builtin_amdgcn_s_barrier();
        readB(0, 1, Bf1);
        __builtin_amdgcn_s_barrier();
        mfma16(0, 1, Bf1);
        __builtin_amdgcn_s_barrier();
        readA(0, 1); stageHT(T + 2, 1, 0);
        __builtin_amdgcn_s_barrier();
        mfma16(1, 1, Bf1);
        __builtin_amdgcn_s_barrier();
        stageHT(T + 2, 1, 1); stageHT(T + 2, 0, 0);
        __builtin_amdgcn_s_barrier();
        mfma16(1, 0, Bf0);
        if (it < 7) { asm volatile("s_waitcnt vmcnt(6)" ::: "memory"); }
        else        { asm volatile("s_waitcnt vmcnt(0)" ::: "memory"); }
        __builtin_amdgcn_s_barrier();
        readA(1, 0); readB(1, 0, Bf0); stageHT(T + 2, 0, 1);
        __builtin_amdgcn_s_barrier();
        mfma16(0, 0, Bf0);
        __builtin_amdgcn_s_barrier();
        readB(1, 1, Bf1);
        __builtin_amdgcn_s_barrier();
        mfma16(0, 1, Bf1);
        __builtin_amdgcn_s_barrier();
        readA(1, 1); stageHT(T + 3, 1, 0);
        __builtin_amdgcn_s_barrier();
        mfma16(1, 1, Bf1);
        __builtin_amdgcn_s_barrier();
        stageHT(T + 3, 1, 1); stageHT(T + 3, 0, 0);
        __builtin_amdgcn_s_barrier();
        mfma16(1, 0, Bf0);
        if (it < 7) { asm volatile("s_waitcnt vmcnt(6)" ::: "memory"); }
        __builtin_amdgcn_s_barrier();
    }

#pragma unroll
    for (int fm = 0; fm < 8; ++fm) {
#pragma unroll
        for (int fn = 0; fn < 4; ++fn) {
            int n_g = n0 + wn * 64 + fn * 16 + l15;
            int which = n_g >> 10;
            int h = (n_g >> 6) & 15;
            int d = n_g & 63;
            int m_base = m0 + wm * 128 + fm * 16 + q16 * 4;
            int b = m_base >> 11;
            int nn0 = m_base & 2047;
            if (which == 2) {
                uint2 pk;
                pk.x = pack2bf(acc[fm][fn][0], acc[fm][fn][1]);
                pk.y = pack2bf(acc[fm][fn][2], acc[fm][fn][3]);
                *(uint2*)(vt + ((size_t)((b * H_ + h) * D_ + d) << 11) + nn0) = pk;
            } else {
                size_t base = ((size_t)((b * H_ + h) * N_ + nn0) << 6) + d;
#pragma unroll
                for (int r = 0; r < 4; ++r) {
                    float v = acc[fm][fn][r];
                    if (which == 0) qo[base + (size_t)r * D_] = f2bf(v * QSCALE);
                    else            ko[base + (size_t)r * D_] = f2bf(v);
                }
            }
        }
    }
}

// ---------------- gemm1: out = A * B^T + bias, 128x64 tiles, DOUBLE-BUFFERED --------------
// r12 ledger: gemm1 ~25us at 340 TF because each K-step was stage -> full drain -> compute
// (zero overlap). Now: attn-style dbuf -- prefetch tile k+1 into buf^1 while computing buf,
// single drain+barrier per step. LDS 48 KB -> still 2 blocks/CU at (256,2). XCD-swizzled.
__global__ __launch_bounds__(256, 2) void gemm_out(
    const u16* __restrict__ A, const u16* __restrict__ Bm,
    const float* __restrict__ bias, float* __restrict__ out) {
    __shared__ u16 As[2][128 * 64];  // 32 KB
    __shared__ u16 Bs[2][64 * 64];   // 16 KB
    const int K = C_, Ncols = C_, ntiles_n = 16;
    const int tid = threadIdx.x, lane = tid & 63, w = tid >> 6;
    const int cpx = gridDim.x >> 3;  // 64
    const int sbid = (blockIdx.x & 7) * cpx + (blockIdx.x >> 3);
    const int bx = sbid % ntiles_n, by = sbid / ntiles_n;
    const int m0 = by * 128, n0 = bx * 64;
    const int wm = w >> 1, wn = w & 1;
    const int q16 = lane >> 4, l15 = lane & 15;
    const int r0 = lane >> 3, c0 = (lane & 7) * 8;
    f32x4 acc[4][2] = {};

    auto stage = [&](int k0, int buf) {
#pragma unroll
        for (int i = 0; i < 4; ++i) {
            int blk = w * 4 + i;   // 0..15: A chunks
            int r = blk * 8 + r0;
            async_copy16(A + (size_t)(m0 + r) * K + k0 + c0, (char*)As[buf] + blk * 1024);
        }
#pragma unroll
        for (int i = 0; i < 2; ++i) {
            int blk = w * 2 + i;   // 0..7: B chunks
            int r = blk * 8 + r0;
            async_copy16(Bm + (size_t)(n0 + r) * K + k0 + c0, (char*)Bs[buf] + blk * 1024);
        }
    };

    // prologue: stage k0=0 into buf 0, full drain once.
    stage(0, 0);
    __builtin_amdgcn_s_waitcnt(0);
    __syncthreads();

    for (int k0 = 0; k0 < K; k0 += 64) {
        int buf = (k0 >> 6) & 1;
        if (k0 + 64 < K) stage(k0 + 64, buf ^ 1);  // prefetch next tile under compute
#pragma unroll
        for (int ks = 0; ks < 2; ++ks) {
            bf16x8 af[4], bf[2];
#pragma unroll
            for (int i = 0; i < 4; ++i)
                af[i] = *(const bf16x8*)&As[buf][(wm * 64 + i * 16 + l15) * 64 + ks * 32 + q16 * 8];
#pragma unroll
            for (int i = 0; i < 2; ++i)
                bf[i] = *(const bf16x8*)&Bs[buf][(wn * 32 + i * 16 + l15) * 64 + ks * 32 + q16 * 8];
            __builtin_amdgcn_s_setprio(1);
#pragma unroll
            for (int mi = 0; mi < 4; ++mi)
#pragma unroll
                for (int ni = 0; ni < 2; ++ni)
                    acc[mi][ni] = __builtin_amdgcn_mfma_f32_16x16x32_bf16(af[mi], bf[ni], acc[mi][ni], 0, 0, 0);
            __builtin_amdgcn_s_setprio(0);
        }
        // drain prefetch + barrier (prefetch had the whole compute phase to land)
        __builtin_amdgcn_s_waitcnt(0);
        __syncthreads();
    }

#pragma unroll
    for (int mi = 0; mi < 4; ++mi) {
#pragma unroll
        for (int ni = 0; ni < 2; ++ni) {
            int n_g = n0 + wn * 32 + ni * 16 + l15;
#pragma unroll
            for (int r = 0; r < 4; ++r) {
                int m_g = m0 + wm * 64 + mi * 16 + q16 * 4 + r;
                out[(size_t)m_g * Ncols + n_g] = acc[mi][ni][r] + bias[n_g];
            }
        }
    }
}

// ---------------- attention: r5/r9/r11 exact (best measured: 45.0 us) ---------------------
// 32x32 MFMA, in-register P (no Ps LDS), 8 waves x 32 q, grid 256, XCD-swizzled.
// QK C-layout (m74/m101): col=lane&31=q, row=key=(reg&3)+8*(reg>>2)+4*hi.
__global__ __launch_bounds__(512, 1) void attn_kernel(
    const u16* __restrict__ Q, const u16* __restrict__ K,
    const u16* __restrict__ VT, u16* __restrict__ O) {
    __shared__ u16 Ks[2][2][64 * 64];  // [buf][sub][key][d], 16B-block swizzle (mask 7)
    __shared__ u16 Vs[2][2][64 * 64];  // [buf][sub][d][key], 16B-block swizzle (mask 7)
    const int tid = threadIdx.x, lane = tid & 63, w = tid >> 6;
    const int l31 = lane & 31, hi = lane >> 5, l7 = l31 & 7;
    const int bid = blockIdx.x;
    const int bh = (bid & 7) * 4 + (bid >> 6);
    const int q0 = ((bid >> 3) & 7) * 256;
    const size_t head = (size_t)bh * N_ * D_;
    const int lr3 = lane >> 3, lc7 = lane & 7;

    auto stage = [&](int kt, int buf) {
        int key0 = kt * 128;
        int row = w * 8 + lr3;
#pragma unroll
        for (int s = 0; s < 2; ++s) {
            async_copy16(K + head + (size_t)(key0 + s * 64 + row) * D_ + (lc7 ^ lr3) * 8,
                         (char*)Ks[buf][s] + w * 1024);
            async_copy16(VT + head + (size_t)row * N_ + key0 + s * 64 + (lc7 ^ lr3) * 8,
                         (char*)Vs[buf][s] + w * 1024);
        }
    };

    bf16x8 qf[4];
#pragma unroll
    for (int ds = 0; ds < 4; ++ds)
        qf[ds] = *(const bf16x8*)(Q + head + (size_t)(q0 + w * 32 + l31) * D_ + ds * 16 + hi * 8);
    stage(0, 0);
    __builtin_amdgcn_s_waitcnt(0);
    __syncthreads();

    f32x16 o_acc[2] = {};
    float rs = 0.f;

    for (int kt = 0; kt < 16; ++kt) {
        int buf = kt & 1;
        stage((kt + 1) & 15, buf ^ 1);

#pragma unroll
        for (int s = 0; s < 2; ++s) {
#pragma unroll
            for (int kb2 = 0; kb2 < 2; ++kb2) {
                f32x16 st = {};
                __builtin_amdgcn_s_setprio(1);
#pragma unroll
                for (int ds = 0; ds < 4; ++ds) {
                    bf16x8 kf = *(const bf16x8*)&Ks[buf][s][(kb2 * 32 + l31) * 64 + ((ds * 2 + hi) ^ l7) * 8];
                    st = __builtin_amdgcn_mfma_f32_32x32x16_bf16(kf, qf[ds], st, 0, 0, 0);
                }
                __builtin_amdgcn_s_setprio(0);

                float p[16];
#pragma unroll
                for (int i = 0; i < 16; ++i) p[i] = EXP2R(st[i]);
#pragma unroll
                for (int i = 0; i < 16; ++i) rs += p[i];

                unsigned a0 = cvtpk2bf(p[0], p[1]),   b0 = cvtpk2bf(p[4], p[5]);
                unsigned a1 = cvtpk2bf(p[2], p[3]),   b1 = cvtpk2bf(p[6], p[7]);
                unsigned a2 = cvtpk2bf(p[8], p[9]),   b2 = cvtpk2bf(p[12], p[13]);
                unsigned a3 = cvtpk2bf(p[10], p[11]), b3 = cvtpk2bf(p[14], p[15]);
                asm("v_permlane32_swap_b32 %0, %1" : "+v"(a0), "+v"(b0));
                asm("v_permlane32_swap_b32 %0, %1" : "+v"(a1), "+v"(b1));
                asm("v_permlane32_swap_b32 %0, %1" : "+v"(a2), "+v"(b2));
                asm("v_permlane32_swap_b32 %0, %1" : "+v"(a3), "+v"(b3));
                union { u32x4 u; bf16x8 v; } af0, af1;
                af0.u = (u32x4){a0, a1, b0, b1};
                af1.u = (u32x4){a2, a3, b2, b3};

                __builtin_amdgcn_s_setprio(1);
#pragma unroll
                for (int db = 0; db < 2; ++db) {
                    bf16x8 vf0 = *(const bf16x8*)&Vs[buf][s][(db * 32 + l31) * 64 + ((kb2 * 4 + hi) ^ l7) * 8];
                    o_acc[db] = __builtin_amdgcn_mfma_f32_32x32x16_bf16(af0.v, vf0, o_acc[db], 0, 0, 0);
                    bf16x8 vf1 = *(const bf16x8*)&Vs[buf][s][(db * 32 + l31) * 64 + ((kb2 * 4 + 2 + hi) ^ l7) * 8];
                    o_acc[db] = __builtin_amdgcn_mfma_f32_32x32x16_bf16(af1.v, vf1, o_acc[db], 0, 0, 0);
                }
                __builtin_amdgcn_s_setprio(0);
            }
        }

        __builtin_amdgcn_s_waitcnt(0);
        __syncthreads();
    }

    rs += __shfl_xor(rs, 32);
    float rsi = 1.0f / rs;

    const int b = bh >> 4, h = bh & 15;
#pragma unroll
    for (int reg = 0; reg < 16; ++reg) {
        int qrow = (reg & 3) + 8 * (reg >> 2) + 4 * hi;
        float inv = __shfl(rsi, qrow);
        int qg = q0 + w * 32 + qrow;
#pragma unroll
        for (int db = 0; db < 2; ++db) {
            int d = db * 32 + l31;
            O[((size_t)(b * N_ + qg) << 10) + h * 64 + d] = f2bf(o_acc[db][reg] * inv);
        }
    }
}

extern "C" void kernel_launch(void* const* d_in, const int* in_sizes, int n_in,
                              void* d_out, int out_size, void* d_ws, size_t ws_size,
                              hipStream_t stream) {
    const float* x      = (const float*)d_in[0];
    const float* w_qkv  = (const float*)d_in[1];
    const float* w_proj = (const float*)d_in[2];
    const float* b_proj = (const float*)d_in[3];
    float* out = (float*)d_out;

    char* ws = (char*)d_ws;
    const size_t MB = 1024 * 1024;
    u16* x_bf     = (u16*)(ws + 0 * MB);   // 8 MB
    u16* wqkv_bf  = (u16*)(ws + 8 * MB);   // 6 MB
    u16* wproj_bf = (u16*)(ws + 14 * MB);  // 2 MB
    u16* q_bf     = (u16*)(ws + 16 * MB);  // 8 MB [B,H,N,D]
    u16* k_bf     = (u16*)(ws + 24 * MB);  // 8 MB [B,H,N,D]
    u16* vt_bf    = (u16*)(ws + 32 * MB);  // 8 MB [B,H,D,N]
    u16* ao_bf    = (u16*)(ws + 40 * MB);  // 8 MB [B,N,C]

    cast3_kernel<<<8192, 256, 0, stream>>>(x, w_qkv, w_proj, x_bf, wqkv_bf, wproj_bf);

    gemm_qkv8<<<192, 512, 0, stream>>>(x_bf, wqkv_bf, q_bf, k_bf, vt_bf);

    attn_kernel<<<256, 512, 0, stream>>>(q_bf, k_bf, vt_bf, ao_bf);

    gemm_out<<<512, 256, 0, stream>>>(ao_bf, wproj_bf, b_proj, out);
}

// Round 15
// 175.193 us; speedup vs baseline: 2.5703x; 1.0254x over previous
//
#include <hip/hip_runtime.h>

typedef unsigned short u16;
typedef __attribute__((ext_vector_type(8))) short bf16x8;
typedef __attribute__((ext_vector_type(4))) float f32x4;
typedef __attribute__((ext_vector_type(16))) float f32x16;
typedef __attribute__((ext_vector_type(4))) unsigned u32x4;

#define B_ 2
#define N_ 2048
#define C_ 1024
#define H_ 16
#define D_ 64
#define M_ (B_ * N_)  // 4096

// 0.125 * log2(e): fold the 1/sqrt(D) scale and exp->exp2 conversion into Q.
#define QSCALE 0.18033688011114336f

#define EXP2R(x) __builtin_amdgcn_exp2f(x)

__device__ __forceinline__ u16 f2bf(float f) {
    union { float f; unsigned u; } x; x.f = f;
    return (u16)((x.u + 0x8000u) >> 16);
}
__device__ __forceinline__ unsigned pack2bf(float a, float b) {
    union { float f; unsigned u; } x, y; x.f = a; y.f = b;
    return __builtin_amdgcn_perm(y.u + 0x8000u, x.u + 0x8000u, 0x07060302);
}
// single-op pack (RTNE), verified correct in r6
__device__ __forceinline__ unsigned cvtpk2bf(float a, float b) {
    unsigned r;
    asm("v_cvt_pk_bf16_f32 %0, %1, %2" : "=v"(r) : "v"(a), "v"(b));
    return r;
}

__device__ __forceinline__ void async_copy16(const void* gsrc, void* ldst) {
    __builtin_amdgcn_global_load_lds(
        (__attribute__((address_space(1))) void*)gsrc,
        (__attribute__((address_space(3))) void*)ldst,
        16, 0, 0);
}

// ---------------- fused cast fp32 -> bf16 (x, w_qkv, w_proj in one launch) ----------------
__global__ void cast3_kernel(const float* __restrict__ x, const float* __restrict__ wq,
                             const float* __restrict__ wp, u16* __restrict__ xo,
                             u16* __restrict__ wqo, u16* __restrict__ wpo) {
    int b = blockIdx.x;
    const float* s; u16* d;
    if (b < 4096)      { s = x;  d = xo;  }
    else if (b < 7168) { s = wq; d = wqo; b -= 4096; }
    else               { s = wp; d = wpo; b -= 7168; }
    int i = (b * 256 + threadIdx.x) * 4;
    const float4 v = *(const float4*)(s + i);
    uint2 o;
    o.x = pack2bf(v.x, v.y);
    o.y = pack2bf(v.z, v.w);
    *(uint2*)(d + i) = o;
}

// ---------------- gemm0: 8-phase 256x256 schedule (r11, verified WAR-safe) ----------------
// C = A(x_bf [4096,1024]) * B(wqkv_bf [3072,1024])^T, scatter epilogue into q/k/vt.
// grid 192 (16x12), 512 thr (8 waves, 2M x 4N), LDS 128 KB = 2 regions x 4 half-tile slots
// {Ah0,Ah1,Bh0,Bh1} of [128][64] bf16, XOR-swizzled (source (lc7^lr3), read ^l7).
// Ledger: A slots read in ph1+ph3 -> Ah0 stages at ph4/ph8; B slots read ph1+ph2 -> Bh0 at
// ph3/ph7, Bh1 at ph4/ph8. vmcnt(6) at ph4/ph8 completes the next tile before its reads.
__global__ __launch_bounds__(512, 2) void gemm_qkv8(
    const u16* __restrict__ A, const u16* __restrict__ Bm,
    u16* __restrict__ qo, u16* __restrict__ ko, u16* __restrict__ vt) {
    __shared__ u16 L[2][4][8192];  // [region][slot][128*64]
    const int tid = threadIdx.x, lane = tid & 63, w = tid >> 6;  // 8 waves
    const int wm = w >> 2, wn = w & 3;
    const int q16 = lane >> 4, l15 = lane & 15, l7 = lane & 7;
    const int lr3 = lane >> 3, lc7 = lane & 7;
    const int sbid = (blockIdx.x & 7) * 24 + (blockIdx.x >> 3);  // XCD swizzle (192%8==0)
    const int bx = sbid % 12, by = sbid / 12;
    const int m0 = by * 256, n0 = bx * 256;
    const int cswz8 = (lc7 ^ lr3) * 8;

    auto stageHT = [&](int t, int isB, int h) {  // one 16KB half-tile, 2 loads/thread
        if (t > 15) return;
        const u16* src = isB ? Bm : A;
        int base_row = (isB ? n0 : m0) + h * 128;
#pragma unroll
        for (int i = 0; i < 2; ++i) {
            int c = w * 2 + i;  // 1KB chunk 0..15 (8 rows x 128B)
            async_copy16(src + (size_t)(base_row + c * 8 + lr3) * 1024 + t * 64 + cswz8,
                         (char*)L + ((t & 1) * 4 + isB * 2 + h) * 16384 + c * 1024);
        }
    };

    // prologue: tile0 (4 halves) + tile1 (3 halves); drain to 3 HT; barrier.
    stageHT(0, 0, 0); stageHT(0, 1, 0); stageHT(0, 1, 1); stageHT(0, 0, 1);
    stageHT(1, 0, 0); stageHT(1, 1, 0); stageHT(1, 1, 1);
    asm volatile("s_waitcnt vmcnt(6)" ::: "memory");
    __builtin_amdgcn_s_barrier();

    f32x4 acc[8][4] = {};
    const int aRow = l15 * 64;
    const int colsw0 = (q16 ^ l7) * 8, colsw1 = ((4 + q16) ^ l7) * 8;
    const u16* LA[2] = { &L[0][wm][0], &L[1][wm][0] };
    const u16* LB[2] = { &L[0][2 + (wn >> 1)][0], &L[1][2 + (wn >> 1)][0] };
    const int bOff = (wn & 1) * 4096;

    bf16x8 Af[4][2], Bf0[2][2], Bf1[2][2];

    auto readA = [&](int P, int mh) {
#pragma unroll
        for (int i = 0; i < 4; ++i) {
            Af[i][0] = *(const bf16x8*)(LA[P] + (mh * 64 + i * 16) * 64 + aRow + colsw0);
            Af[i][1] = *(const bf16x8*)(LA[P] + (mh * 64 + i * 16) * 64 + aRow + colsw1);
        }
    };
    auto readB = [&](int P, int nh, bf16x8 (*Bf)[2]) {
#pragma unroll
        for (int j = 0; j < 2; ++j) {
            Bf[j][0] = *(const bf16x8*)(LB[P] + bOff + (nh * 32 + j * 16) * 64 + aRow + colsw0);
            Bf[j][1] = *(const bf16x8*)(LB[P] + bOff + (nh * 32 + j * 16) * 64 + aRow + colsw1);
        }
    };
    auto mfma16 = [&](int mh, int nh, bf16x8 (*Bf)[2]) {
        __builtin_amdgcn_s_setprio(1);
#pragma unroll
        for (int i = 0; i < 4; ++i)
#pragma unroll
            for (int j = 0; j < 2; ++j)
#pragma unroll
                for (int ks = 0; ks < 2; ++ks)
                    acc[mh * 4 + i][nh * 2 + j] = __builtin_amdgcn_mfma_f32_16x16x32_bf16(
                        Af[i][ks], Bf[j][ks], acc[mh * 4 + i][nh * 2 + j], 0, 0, 0);
        __builtin_amdgcn_s_setprio(0);
    };

    for (int it = 0; it < 8; ++it) {
        const int T = 2 * it;
        readA(0, 0); readB(0, 0, Bf0); stageHT(T + 1, 0, 1);
        __builtin_amdgcn_s_barrier();
        mfma16(0, 0, Bf0);
        __builtin_amdgcn_s_barrier();
        readB(0, 1, Bf1);
        __builtin_amdgcn_s_barrier();
        mfma16(0, 1, Bf1);
        __builtin_amdgcn_s_barrier();
        readA(0, 1); stageHT(T + 2, 1, 0);
        __builtin_amdgcn_s_barrier();
        mfma16(1, 1, Bf1);
        __builtin_amdgcn_s_barrier();
        stageHT(T + 2, 1, 1); stageHT(T + 2, 0, 0);
        __builtin_amdgcn_s_barrier();
        mfma16(1, 0, Bf0);
        if (it < 7) { asm volatile("s_waitcnt vmcnt(6)" ::: "memory"); }
        else        { asm volatile("s_waitcnt vmcnt(0)" ::: "memory"); }
        __builtin_amdgcn_s_barrier();
        readA(1, 0); readB(1, 0, Bf0); stageHT(T + 2, 0, 1);
        __builtin_amdgcn_s_barrier();
        mfma16(0, 0, Bf0);
        __builtin_amdgcn_s_barrier();
        readB(1, 1, Bf1);
        __builtin_amdgcn_s_barrier();
        mfma16(0, 1, Bf1);
        __builtin_amdgcn_s_barrier();
        readA(1, 1); stageHT(T + 3, 1, 0);
        __builtin_amdgcn_s_barrier();
        mfma16(1, 1, Bf1);
        __builtin_amdgcn_s_barrier();
        stageHT(T + 3, 1, 1); stageHT(T + 3, 0, 0);
        __builtin_amdgcn_s_barrier();
        mfma16(1, 0, Bf0);
        if (it < 7) { asm volatile("s_waitcnt vmcnt(6)" ::: "memory"); }
        __builtin_amdgcn_s_barrier();
    }

#pragma unroll
    for (int fm = 0; fm < 8; ++fm) {
#pragma unroll
        for (int fn = 0; fn < 4; ++fn) {
            int n_g = n0 + wn * 64 + fn * 16 + l15;
            int which = n_g >> 10;
            int h = (n_g >> 6) & 15;
            int d = n_g & 63;
            int m_base = m0 + wm * 128 + fm * 16 + q16 * 4;
            int b = m_base >> 11;
            int nn0 = m_base & 2047;
            if (which == 2) {
                uint2 pk;
                pk.x = pack2bf(acc[fm][fn][0], acc[fm][fn][1]);
                pk.y = pack2bf(acc[fm][fn][2], acc[fm][fn][3]);
                *(uint2*)(vt + ((size_t)((b * H_ + h) * D_ + d) << 11) + nn0) = pk;
            } else {
                size_t base = ((size_t)((b * H_ + h) * N_ + nn0) << 6) + d;
#pragma unroll
                for (int r = 0; r < 4; ++r) {
                    float v = acc[fm][fn][r];
                    if (which == 0) qo[base + (size_t)r * D_] = f2bf(v * QSCALE);
                    else            ko[base + (size_t)r * D_] = f2bf(v);
                }
            }
        }
    }
}

// ---------------- gemm1: out = A * B^T + bias, 64x64 tiles, 4 blocks/CU -------------------
// r14 post-mortem: dbuf was neutral -- gemm1 is OCCUPANCY-limited, not overlap-limited.
// 64x64 tiles -> 64x16 = 1024 blocks = 4 blocks/CU (16 waves/CU = 4 waves/SIMD, double the
// latency-hiding pool; 4 independent block barriers per CU decorrelate drains). Simple
// proven 2-phase staging; LDS 16 KB/block. XCD-swizzled (1024 % 8 == 0).
__global__ __launch_bounds__(256, 4) void gemm_out(
    const u16* __restrict__ A, const u16* __restrict__ Bm,
    const float* __restrict__ bias, float* __restrict__ out) {
    __shared__ u16 As[64 * 64];  // 8 KB
    __shared__ u16 Bs[64 * 64];  // 8 KB
    const int K = C_, Ncols = C_, ntiles_n = 16;
    const int tid = threadIdx.x, lane = tid & 63, w = tid >> 6;  // 4 waves
    const int cpx = gridDim.x >> 3;  // 128
    const int sbid = (blockIdx.x & 7) * cpx + (blockIdx.x >> 3);
    const int bx = sbid % ntiles_n, by = sbid / ntiles_n;
    const int m0 = by * 64, n0 = bx * 64;
    const int wm = w >> 1, wn = w & 1;
    const int q16 = lane >> 4, l15 = lane & 15;
    const int r0 = lane >> 3, c0 = (lane & 7) * 8;
    f32x4 acc[2][2] = {};

    for (int k0 = 0; k0 < K; k0 += 64) {
#pragma unroll
        for (int i = 0; i < 2; ++i) {
            int blk = w * 2 + i;   // 0..7: A chunks (8 rows x 128B each)
            int r = blk * 8 + r0;
            async_copy16(A + (size_t)(m0 + r) * K + k0 + c0, (char*)As + blk * 1024);
            async_copy16(Bm + (size_t)(n0 + r) * K + k0 + c0, (char*)Bs + blk * 1024);
        }
        __builtin_amdgcn_s_waitcnt(0);
        __syncthreads();
#pragma unroll
        for (int ks = 0; ks < 2; ++ks) {
            bf16x8 af[2], bf[2];
#pragma unroll
            for (int i = 0; i < 2; ++i) {
                af[i] = *(const bf16x8*)&As[(wm * 32 + i * 16 + l15) * 64 + ks * 32 + q16 * 8];
                bf[i] = *(const bf16x8*)&Bs[(wn * 32 + i * 16 + l15) * 64 + ks * 32 + q16 * 8];
            }
            __builtin_amdgcn_s_setprio(1);
#pragma unroll
            for (int mi = 0; mi < 2; ++mi)
#pragma unroll
                for (int ni = 0; ni < 2; ++ni)
                    acc[mi][ni] = __builtin_amdgcn_mfma_f32_16x16x32_bf16(af[mi], bf[ni], acc[mi][ni], 0, 0, 0);
            __builtin_amdgcn_s_setprio(0);
        }
        __syncthreads();
    }

#pragma unroll
    for (int mi = 0; mi < 2; ++mi) {
#pragma unroll
        for (int ni = 0; ni < 2; ++ni) {
            int n_g = n0 + wn * 32 + ni * 16 + l15;
#pragma unroll
            for (int r = 0; r < 4; ++r) {
                int m_g = m0 + wm * 32 + mi * 16 + q16 * 4 + r;
                out[(size_t)m_g * Ncols + n_g] = acc[mi][ni][r] + bias[n_g];
            }
        }
    }
}

// ---------------- attention: r5/r9/r11 exact (best measured: 45.0 us) ---------------------
// 32x32 MFMA, in-register P (no Ps LDS), 8 waves x 32 q, grid 256, XCD-swizzled.
// QK C-layout (m74/m101): col=lane&31=q, row=key=(reg&3)+8*(reg>>2)+4*hi.
__global__ __launch_bounds__(512, 1) void attn_kernel(
    const u16* __restrict__ Q, const u16* __restrict__ K,
    const u16* __restrict__ VT, u16* __restrict__ O) {
    __shared__ u16 Ks[2][2][64 * 64];  // [buf][sub][key][d], 16B-block swizzle (mask 7)
    __shared__ u16 Vs[2][2][64 * 64];  // [buf][sub][d][key], 16B-block swizzle (mask 7)
    const int tid = threadIdx.x, lane = tid & 63, w = tid >> 6;
    const int l31 = lane & 31, hi = lane >> 5, l7 = l31 & 7;
    const int bid = blockIdx.x;
    const int bh = (bid & 7) * 4 + (bid >> 6);
    const int q0 = ((bid >> 3) & 7) * 256;
    const size_t head = (size_t)bh * N_ * D_;
    const int lr3 = lane >> 3, lc7 = lane & 7;

    auto stage = [&](int kt, int buf) {
        int key0 = kt * 128;
        int row = w * 8 + lr3;
#pragma unroll
        for (int s = 0; s < 2; ++s) {
            async_copy16(K + head + (size_t)(key0 + s * 64 + row) * D_ + (lc7 ^ lr3) * 8,
                         (char*)Ks[buf][s] + w * 1024);
            async_copy16(VT + head + (size_t)row * N_ + key0 + s * 64 + (lc7 ^ lr3) * 8,
                         (char*)Vs[buf][s] + w * 1024);
        }
    };

    bf16x8 qf[4];
#pragma unroll
    for (int ds = 0; ds < 4; ++ds)
        qf[ds] = *(const bf16x8*)(Q + head + (size_t)(q0 + w * 32 + l31) * D_ + ds * 16 + hi * 8);
    stage(0, 0);
    __builtin_amdgcn_s_waitcnt(0);
    __syncthreads();

    f32x16 o_acc[2] = {};
    float rs = 0.f;

    for (int kt = 0; kt < 16; ++kt) {
        int buf = kt & 1;
        stage((kt + 1) & 15, buf ^ 1);

#pragma unroll
        for (int s = 0; s < 2; ++s) {
#pragma unroll
            for (int kb2 = 0; kb2 < 2; ++kb2) {
                f32x16 st = {};
                __builtin_amdgcn_s_setprio(1);
#pragma unroll
                for (int ds = 0; ds < 4; ++ds) {
                    bf16x8 kf = *(const bf16x8*)&Ks[buf][s][(kb2 * 32 + l31) * 64 + ((ds * 2 + hi) ^ l7) * 8];
                    st = __builtin_amdgcn_mfma_f32_32x32x16_bf16(kf, qf[ds], st, 0, 0, 0);
                }
                __builtin_amdgcn_s_setprio(0);

                float p[16];
#pragma unroll
                for (int i = 0; i < 16; ++i) p[i] = EXP2R(st[i]);
#pragma unroll
                for (int i = 0; i < 16; ++i) rs += p[i];

                unsigned a0 = cvtpk2bf(p[0], p[1]),   b0 = cvtpk2bf(p[4], p[5]);
                unsigned a1 = cvtpk2bf(p[2], p[3]),   b1 = cvtpk2bf(p[6], p[7]);
                unsigned a2 = cvtpk2bf(p[8], p[9]),   b2 = cvtpk2bf(p[12], p[13]);
                unsigned a3 = cvtpk2bf(p[10], p[11]), b3 = cvtpk2bf(p[14], p[15]);
                asm("v_permlane32_swap_b32 %0, %1" : "+v"(a0), "+v"(b0));
                asm("v_permlane32_swap_b32 %0, %1" : "+v"(a1), "+v"(b1));
                asm("v_permlane32_swap_b32 %0, %1" : "+v"(a2), "+v"(b2));
                asm("v_permlane32_swap_b32 %0, %1" : "+v"(a3), "+v"(b3));
                union { u32x4 u; bf16x8 v; } af0, af1;
                af0.u = (u32x4){a0, a1, b0, b1};
                af1.u = (u32x4){a2, a3, b2, b3};

                __builtin_amdgcn_s_setprio(1);
#pragma unroll
                for (int db = 0; db < 2; ++db) {
                    bf16x8 vf0 = *(const bf16x8*)&Vs[buf][s][(db * 32 + l31) * 64 + ((kb2 * 4 + hi) ^ l7) * 8];
                    o_acc[db] = __builtin_amdgcn_mfma_f32_32x32x16_bf16(af0.v, vf0, o_acc[db], 0, 0, 0);
                    bf16x8 vf1 = *(const bf16x8*)&Vs[buf][s][(db * 32 + l31) * 64 + ((kb2 * 4 + 2 + hi) ^ l7) * 8];
                    o_acc[db] = __builtin_amdgcn_mfma_f32_32x32x16_bf16(af1.v, vf1, o_acc[db], 0, 0, 0);
                }
                __builtin_amdgcn_s_setprio(0);
            }
        }

        __builtin_amdgcn_s_waitcnt(0);
        __syncthreads();
    }

    rs += __shfl_xor(rs, 32);
    float rsi = 1.0f / rs;

    const int b = bh >> 4, h = bh & 15;
#pragma unroll
    for (int reg = 0; reg < 16; ++reg) {
        int qrow = (reg & 3) + 8 * (reg >> 2) + 4 * hi;
        float inv = __shfl(rsi, qrow);
        int qg = q0 + w * 32 + qrow;
#pragma unroll
        for (int db = 0; db < 2; ++db) {
            int d = db * 32 + l31;
            O[((size_t)(b * N_ + qg) << 10) + h * 64 + d] = f2bf(o_acc[db][reg] * inv);
        }
    }
}

extern "C" void kernel_launch(void* const* d_in, const int* in_sizes, int n_in,
                              void* d_out, int out_size, void* d_ws, size_t ws_size,
                              hipStream_t stream) {
    const float* x      = (const float*)d_in[0];
    const float* w_qkv  = (const float*)d_in[1];
    const float* w_proj = (const float*)d_in[2];
    const float* b_proj = (const float*)d_in[3];
    float* out = (float*)d_out;

    char* ws = (char*)d_ws;
    const size_t MB = 1024 * 1024;
    u16* x_bf     = (u16*)(ws + 0 * MB);   // 8 MB
    u16* wqkv_bf  = (u16*)(ws + 8 * MB);   // 6 MB
    u16* wproj_bf = (u16*)(ws + 14 * MB);  // 2 MB
    u16* q_bf     = (u16*)(ws + 16 * MB);  // 8 MB [B,H,N,D]
    u16* k_bf     = (u16*)(ws + 24 * MB);  // 8 MB [B,H,N,D]
    u16* vt_bf    = (u16*)(ws + 32 * MB);  // 8 MB [B,H,D,N]
    u16* ao_bf    = (u16*)(ws + 40 * MB);  // 8 MB [B,N,C]

    cast3_kernel<<<8192, 256, 0, stream>>>(x, w_qkv, w_proj, x_bf, wqkv_bf, wproj_bf);

    gemm_qkv8<<<192, 512, 0, stream>>>(x_bf, wqkv_bf, q_bf, k_bf, vt_bf);

    attn_kernel<<<256, 512, 0, stream>>>(q_bf, k_bf, vt_bf, ao_bf);

    gemm_out<<<64 * 16, 256, 0, stream>>>(ao_bf, wproj_bf, b_proj, out);
}